// Round 13
// baseline (115.013 us; speedup 1.0000x reference)
//
#include <hip/hip_runtime.h>
#include <hip/hip_fp16.h>
#include <math.h>

#define FEATD 128
#define NNODES 10000
#define NBATCH 4
#define NROWS (NBATCH*NNODES)   // 40000

// ws layout (float slots, 4B each)
#define OFF_I1   0                     // 1/sigma1
#define OFF_W1L  8                     // w1last normalized [32] f32
#define OFF_W2   64                    // W2 normalized [32*32] f32 (fallback only)
#define OFF_W3   1088                  // W3 normalized [32] f32
#define OFF_W2H  1120                  // W2 normalized half2 [512 uint slots]
#define OFF_P16  4096                  // P16 raw proj [40000][64] half (5.12 MB)
#define P16_FLOATS (NROWS*64/2)        // 1,280,000 float slots
#define OFF_FQ   (OFF_P16 + P16_FLOATS) // featq: fp8 [40000][128] (5.12MB) or f16 (10.24MB)
#define F16_FLOATS (NROWS*FEATD/2)     // worst case float slots
#define OFF_FBWT OFF_P16               // fallback: normalized Wt[128][64] f32

#define WSTRIDE 68                     // padded k-row stride (bank-conflict fix, R8-verified)

typedef _Float16 h2 __attribute__((ext_vector_type(2)));
union U32H2 { unsigned u; h2 h; };
union U4H2  { uint4 u; h2 h[4]; };

#if defined(__has_builtin)
#if __has_builtin(__builtin_amdgcn_fdot2)
#define HAVE_FDOT2 1
#endif
#if __has_builtin(__builtin_amdgcn_cvt_pk_f32_fp8) && __has_builtin(__builtin_amdgcn_cvt_pk_fp8_f32)
#define HAVE_FP8 1
#endif
#endif

__device__ __forceinline__ float fdot2f(h2 a, h2 b, float c) {
#ifdef HAVE_FDOT2
  return __builtin_amdgcn_fdot2(a, b, c, false);
#else
  return c + (float)a[0] * (float)b[0] + (float)a[1] * (float)b[1];
#endif
}

__device__ __forceinline__ float bfly64(float x) {
  x += __shfl_xor(x, 1, 64);
  x += __shfl_xor(x, 2, 64);
  x += __shfl_xor(x, 4, 64);
  x += __shfl_xor(x, 8, 64);
  x += __shfl_xor(x, 16, 64);
  x += __shfl_xor(x, 32, 64);
  return x;
}

#ifdef HAVE_FP8
typedef float floatx2 __attribute__((ext_vector_type(2)));
__device__ __forceinline__ float ssd_fp8_w(unsigned aw, unsigned bw, float s) {
  floatx2 al = __builtin_amdgcn_cvt_pk_f32_fp8((int)aw, false);
  floatx2 ah = __builtin_amdgcn_cvt_pk_f32_fp8((int)aw, true);
  floatx2 bl = __builtin_amdgcn_cvt_pk_f32_fp8((int)bw, false);
  floatx2 bh = __builtin_amdgcn_cvt_pk_f32_fp8((int)bw, true);
  float d0 = al[0] - bl[0], d1 = al[1] - bl[1];
  float d2 = ah[0] - bh[0], d3 = ah[1] - bh[1];
  return s + d0 * d0 + d1 * d1 + d2 * d2 + d3 * d3;
}
__device__ __forceinline__ float grp_dist_fp8(uint2 au, uint2 bu) {
  float ssd = ssd_fp8_w(au.x, bu.x, 0.f);
  ssd = ssd_fp8_w(au.y, bu.y, ssd);
  ssd += __shfl_xor(ssd, 1, 64);
  ssd += __shfl_xor(ssd, 2, 64);
  ssd += __shfl_xor(ssd, 4, 64);
  ssd += __shfl_xor(ssd, 8, 64);
  return sqrtf(ssd);
}
#endif

// ---------------- single-wave register spectral, batched butterflies (R12-verified) ----------------
__global__ __launch_bounds__(64, 1) void spectral64(const float* __restrict__ W1,
                                                    const float* __restrict__ W2,
                                                    const float* __restrict__ W3,
                                                    float* __restrict__ ws) {
  int lane = threadIdx.x;

  // ---- sigma1: W1 is 32x257; lane holds cols {lane, lane+64, lane+128, lane+192} ----
  float col[4][32];
  float c256[32];
  #pragma unroll
  for (int m = 0; m < 4; ++m)
    #pragma unroll
    for (int j = 0; j < 32; ++j)
      col[m][j] = W1[j * 257 + 64 * m + lane];
  #pragma unroll
  for (int j = 0; j < 32; ++j) c256[j] = W1[j * 257 + 256];

  float u[32];
  #pragma unroll
  for (int j = 0; j < 32; ++j) u[j] = 1.0f;
  float invu = 0.17677669529663687f;   // 1/sqrt(32)
  float nu = 0.f;

  for (int it = 0; it < 5; ++it) {
    float v0 = 0.f, v1 = 0.f, v2 = 0.f, v3 = 0.f, a4 = 0.f;
    #pragma unroll
    for (int j = 0; j < 32; ++j) {
      v0 += col[0][j] * u[j];
      v1 += col[1][j] * u[j];
      v2 += col[2][j] * u[j];
      v3 += col[3][j] * u[j];
      a4 += c256[j] * u[j];
    }
    v0 *= invu; v1 *= invu; v2 *= invu; v3 *= invu;
    float v4 = (lane == 0) ? a4 * invu : 0.f;
    float nv = v0 * v0 + v1 * v1 + v2 * v2 + v3 * v3 + v4 * v4;
    nv = bfly64(nv);
    float invv = 1.0f / (sqrtf(nv) + 1e-12f);

    float b[32];
    #pragma unroll
    for (int j = 0; j < 32; ++j)
      b[j] = (col[0][j] * v0 + col[1][j] * v1 + col[2][j] * v2 +
              col[3][j] * v3 + c256[j] * v4) * invv;
    #pragma unroll
    for (int off = 1; off < 64; off <<= 1) {
      #pragma unroll
      for (int j = 0; j < 32; ++j) b[j] += __shfl_xor(b[j], off, 64);
    }
    nu = 0.f;
    #pragma unroll
    for (int j = 0; j < 32; ++j) { u[j] = b[j]; nu += b[j] * b[j]; }
    invu = 1.0f / (sqrtf(nu) + 1e-12f);
  }
  float sig1 = nu * invu;
  float i1 = 1.0f / sig1;
  if (lane == 0) {
    ws[OFF_I1] = i1;
    #pragma unroll
    for (int j = 0; j < 32; ++j) ws[OFF_W1L + j] = c256[j] * i1;
  }

  // ---- sigma2: W2 is 32x32; lane<32 holds column lane ----
  float wc[32];
  #pragma unroll
  for (int j = 0; j < 32; ++j)
    wc[j] = (lane < 32) ? W2[j * 32 + (lane & 31)] : 0.f;

  float u2[32];
  #pragma unroll
  for (int j = 0; j < 32; ++j) u2[j] = 1.0f;
  float invu2 = 0.17677669529663687f;
  float nu2 = 0.f;

  for (int it = 0; it < 5; ++it) {
    float a = 0.f;
    #pragma unroll
    for (int j = 0; j < 32; ++j) a += wc[j] * u2[j];
    a *= invu2;
    float nv = bfly64(a * a);
    float invv = 1.0f / (sqrtf(nv) + 1e-12f);
    float b[32];
    #pragma unroll
    for (int j = 0; j < 32; ++j) b[j] = wc[j] * a * invv;
    #pragma unroll
    for (int off = 1; off < 64; off <<= 1) {
      #pragma unroll
      for (int j = 0; j < 32; ++j) b[j] += __shfl_xor(b[j], off, 64);
    }
    nu2 = 0.f;
    #pragma unroll
    for (int j = 0; j < 32; ++j) { u2[j] = b[j]; nu2 += b[j] * b[j]; }
    invu2 = 1.0f / (sqrtf(nu2) + 1e-12f);
  }
  float sig2 = nu2 * invu2;
  float i2 = 1.0f / sig2;

  unsigned* w2h = (unsigned*)(ws + OFF_W2H);
  #pragma unroll
  for (int j = 0; j < 32; ++j) {
    float val = wc[j] * i2;
    float oth = __shfl_xor(val, 1, 64);
    if (lane < 32 && (lane & 1) == 0) {
      U32H2 pk;
      pk.h[0] = (_Float16)val;
      pk.h[1] = (_Float16)oth;
      w2h[j * 16 + (lane >> 1)] = pk.u;
    }
  }

  // ---- sigma3 = ||W3|| exactly ----
  float w3v = (lane < 32) ? W3[lane & 31] : 0.f;
  float s3 = bfly64(w3v * w3v);
  if (lane < 32) ws[OFF_W3 + lane] = w3v / (sqrtf(s3) + 1e-12f);
}

// ---------------- projection kernel (R8/R11-verified structure, standalone) ----------------
// 625 blocks, 4 rows/thread, direct global feat reads, padded W1^T LDS, fp8 copy folded in.
__global__ __launch_bounds__(256, 4) void proj_kernel(const float* __restrict__ feat,
                                                      const float* __restrict__ W1,
                                                      float* __restrict__ ws,
                                                      int doFQ) {
  __shared__ float sA[128 * WSTRIDE];   // 34.8 KB
  int tid = threadIdx.x;

  // stage RAW W1 transposed with padded stride:
  //   sA[k*WSTRIDE + j]      = W1[j][k]        (k<128, j<32)   [src half]
  //   sA[k*WSTRIDE + 32 + j] = W1[j][128+k]                    [tgt half]
  for (int idx = tid; idx < 32 * 257; idx += 256) {
    int j = idx / 257, c = idx - j * 257;
    float w = W1[idx];
    if (c < 128) sA[c * WSTRIDE + j] = w;
    else if (c < 256) sA[(c - 128) * WSTRIDE + 32 + j] = w;
  }
  __syncthreads();

  __half* p16 = (__half*)(ws + OFF_P16);
  char* fq = (char*)(ws + OFF_FQ);
  int rg = tid >> 4;              // 0..15 row group
  int jg = (tid & 15) << 2;       // 0,4,...,60 output slice (4 wide)
  int slice = tid & 15;           // owns k4 in {2*slice, 2*slice+1} for quantized write
  int r0 = blockIdx.x * 64 + rg * 4;   // 625*64 = 40000 exact
  const float4* F0 = (const float4*)&feat[(size_t)(r0 + 0) * FEATD];
  const float4* F1 = (const float4*)&feat[(size_t)(r0 + 1) * FEATD];
  const float4* F2 = (const float4*)&feat[(size_t)(r0 + 2) * FEATD];
  const float4* F3 = (const float4*)&feat[(size_t)(r0 + 3) * FEATD];
  float acc[4][4] = {{0,0,0,0},{0,0,0,0},{0,0,0,0},{0,0,0,0}};

  #pragma unroll 2
  for (int k4 = 0; k4 < 32; ++k4) {
    float4 f0 = F0[k4], f1 = F1[k4], f2 = F2[k4], f3 = F3[k4];
    if (doFQ && (k4 >> 1) == slice) {
#ifdef HAVE_FP8
      unsigned w;
      w = __builtin_amdgcn_cvt_pk_fp8_f32(f0.x, f0.y, 0, false);
      w = __builtin_amdgcn_cvt_pk_fp8_f32(f0.z, f0.w, (int)w, true);
      *(unsigned*)(fq + (size_t)(r0 + 0) * 128 + (size_t)k4 * 4) = w;
      w = __builtin_amdgcn_cvt_pk_fp8_f32(f1.x, f1.y, 0, false);
      w = __builtin_amdgcn_cvt_pk_fp8_f32(f1.z, f1.w, (int)w, true);
      *(unsigned*)(fq + (size_t)(r0 + 1) * 128 + (size_t)k4 * 4) = w;
      w = __builtin_amdgcn_cvt_pk_fp8_f32(f2.x, f2.y, 0, false);
      w = __builtin_amdgcn_cvt_pk_fp8_f32(f2.z, f2.w, (int)w, true);
      *(unsigned*)(fq + (size_t)(r0 + 2) * 128 + (size_t)k4 * 4) = w;
      w = __builtin_amdgcn_cvt_pk_fp8_f32(f3.x, f3.y, 0, false);
      w = __builtin_amdgcn_cvt_pk_fp8_f32(f3.z, f3.w, (int)w, true);
      *(unsigned*)(fq + (size_t)(r0 + 3) * 128 + (size_t)k4 * 4) = w;
#else
      U32H2 a, b; uint2 pk;
      a.h[0]=(_Float16)f0.x; a.h[1]=(_Float16)f0.y; b.h[0]=(_Float16)f0.z; b.h[1]=(_Float16)f0.w;
      pk.x=a.u; pk.y=b.u; *(uint2*)(fq + (size_t)(r0+0)*256 + (size_t)k4*8) = pk;
      a.h[0]=(_Float16)f1.x; a.h[1]=(_Float16)f1.y; b.h[0]=(_Float16)f1.z; b.h[1]=(_Float16)f1.w;
      pk.x=a.u; pk.y=b.u; *(uint2*)(fq + (size_t)(r0+1)*256 + (size_t)k4*8) = pk;
      a.h[0]=(_Float16)f2.x; a.h[1]=(_Float16)f2.y; b.h[0]=(_Float16)f2.z; b.h[1]=(_Float16)f2.w;
      pk.x=a.u; pk.y=b.u; *(uint2*)(fq + (size_t)(r0+2)*256 + (size_t)k4*8) = pk;
      a.h[0]=(_Float16)f3.x; a.h[1]=(_Float16)f3.y; b.h[0]=(_Float16)f3.z; b.h[1]=(_Float16)f3.w;
      pk.x=a.u; pk.y=b.u; *(uint2*)(fq + (size_t)(r0+3)*256 + (size_t)k4*8) = pk;
#endif
    }
    #pragma unroll
    for (int kk = 0; kk < 4; ++kk) {
      int k = 4 * k4 + kk;
      float4 w = *(const float4*)&sA[k * WSTRIDE + jg];
      float e0 = (kk == 0) ? f0.x : (kk == 1) ? f0.y : (kk == 2) ? f0.z : f0.w;
      float e1 = (kk == 0) ? f1.x : (kk == 1) ? f1.y : (kk == 2) ? f1.z : f1.w;
      float e2 = (kk == 0) ? f2.x : (kk == 1) ? f2.y : (kk == 2) ? f2.z : f2.w;
      float e3 = (kk == 0) ? f3.x : (kk == 1) ? f3.y : (kk == 2) ? f3.z : f3.w;
      acc[0][0] += e0 * w.x; acc[0][1] += e0 * w.y; acc[0][2] += e0 * w.z; acc[0][3] += e0 * w.w;
      acc[1][0] += e1 * w.x; acc[1][1] += e1 * w.y; acc[1][2] += e1 * w.z; acc[1][3] += e1 * w.w;
      acc[2][0] += e2 * w.x; acc[2][1] += e2 * w.y; acc[2][2] += e2 * w.z; acc[2][3] += e2 * w.w;
      acc[3][0] += e3 * w.x; acc[3][1] += e3 * w.y; acc[3][2] += e3 * w.z; acc[3][3] += e3 * w.w;
    }
  }
  #pragma unroll
  for (int r = 0; r < 4; ++r) {
    U32H2 a, b;
    a.h[0] = (_Float16)acc[r][0]; a.h[1] = (_Float16)acc[r][1];
    b.h[0] = (_Float16)acc[r][2]; b.h[1] = (_Float16)acc[r][3];
    uint2 o; o.x = a.u; o.y = b.u;
    *(uint2*)((char*)p16 + (size_t)(r0 + r) * 128 + (size_t)jg * 2) = o;
  }
}

// ---------------- edge kernel helpers ----------------
__device__ __forceinline__ float grp_dist_f16(uint4 au, uint4 bu) {
  U4H2 a, b; a.u = au; b.u = bu;
  float ssd = 0.f;
  #pragma unroll
  for (int p = 0; p < 4; ++p) { h2 d = a.h[p] - b.h[p]; ssd = fdot2f(d, d, ssd); }
  ssd += __shfl_xor(ssd, 1, 64);
  ssd += __shfl_xor(ssd, 2, 64);
  ssd += __shfl_xor(ssd, 4, 64);
  ssd += __shfl_xor(ssd, 8, 64);
  return sqrtf(ssd);
}

__device__ __forceinline__ unsigned h1pack(unsigned puv, unsigned quv, float dist, float i1,
                                           float w1l0, float w1l1, float bb0, float bb1) {
  U32H2 p, q; p.u = puv; q.u = quv;
  float h0  = fmaxf(fmaf((float)p.h[0] + (float)q.h[0], i1, fmaf(dist, w1l0, bb0)), 0.f);
  float h1v = fmaxf(fmaf((float)p.h[1] + (float)q.h[1], i1, fmaf(dist, w1l1, bb1)), 0.f);
  U32H2 r; r.h[0] = (_Float16)h0; r.h[1] = (_Float16)h1v;
  return r.u;
}

// ---------------- fused edge kernel (R11 structure, unchanged) ----------------
template <bool FQ>
__global__ __launch_bounds__(256, 8) void edge_fused(const float* __restrict__ feat,
                                                     const float* __restrict__ ws,
                                                     const float* __restrict__ b1,
                                                     const float* __restrict__ b2,
                                                     const float* __restrict__ b3,
                                                     const int* __restrict__ bids,
                                                     const int* __restrict__ srcs,
                                                     const int* __restrict__ tgts,
                                                     float* __restrict__ out, int E) {
  __shared__ unsigned ht[256 * 17];
  __shared__ int sRS[256], sRT[256];
  int tid = threadIdx.x;
  int lane = tid & 15;
  int grp  = tid >> 4;

  const char*  featq = (const char*)(ws + OFF_FQ);
  const __half* p16  = (const __half*)(ws + OFF_P16);
  const unsigned* w2h = (const unsigned*)(ws + OFF_W2H);

  float i1 = ws[OFF_I1];
  int j0 = 2 * lane;
  float w1l0 = ws[OFF_W1L + j0];
  float w1l1 = ws[OFF_W1L + j0 + 1];
  float bb0  = b1[j0];
  float bb1  = b1[j0 + 1];
  float bias3 = b3[0];

  for (int base = blockIdx.x * 256; base < E; base += gridDim.x * 256) {
    int e0 = base + tid;
    if (e0 < E) {
      int b = bids[e0];
      sRS[tid] = b * NNODES + srcs[e0];
      sRT[tid] = b * NNODES + tgts[e0];
    }
    __syncthreads();

    if (FQ && (base + 256 <= E)) {
      #pragma unroll 1
      for (int rr = 0; rr < 8; ++rr) {
        int el0 = (rr * 2 + 0) * 16 + grp;
        int el1 = (rr * 2 + 1) * 16 + grp;
        int rs0 = sRS[el0], rt0 = sRT[el0];
        int rs1 = sRS[el1], rt1 = sRT[el1];
#ifdef HAVE_FP8
        uint2 a0 = *(const uint2*)(featq + ((size_t)rs0 << 7) + (lane << 3));
        uint2 c0 = *(const uint2*)(featq + ((size_t)rt0 << 7) + (lane << 3));
        uint2 a1 = *(const uint2*)(featq + ((size_t)rs1 << 7) + (lane << 3));
        uint2 c1 = *(const uint2*)(featq + ((size_t)rt1 << 7) + (lane << 3));
#else
        uint4 a0 = *(const uint4*)(featq + ((size_t)rs0 << 8) + (lane << 4));
        uint4 c0 = *(const uint4*)(featq + ((size_t)rt0 << 8) + (lane << 4));
        uint4 a1 = *(const uint4*)(featq + ((size_t)rs1 << 8) + (lane << 4));
        uint4 c1 = *(const uint4*)(featq + ((size_t)rt1 << 8) + (lane << 4));
#endif
        unsigned pu0 = *(const unsigned*)((const char*)p16 + ((size_t)rs0 << 7) + (lane << 2));
        unsigned qu0 = *(const unsigned*)((const char*)p16 + ((size_t)rt0 << 7) + 64 + (lane << 2));
        unsigned pu1 = *(const unsigned*)((const char*)p16 + ((size_t)rs1 << 7) + (lane << 2));
        unsigned qu1 = *(const unsigned*)((const char*)p16 + ((size_t)rt1 << 7) + 64 + (lane << 2));
#ifdef HAVE_FP8
        float d0 = grp_dist_fp8(a0, c0);
        float d1 = grp_dist_fp8(a1, c1);
#else
        float d0 = grp_dist_f16(a0, c0);
        float d1 = grp_dist_f16(a1, c1);
#endif
        ht[el0 * 17 + lane] = h1pack(pu0, qu0, d0, i1, w1l0, w1l1, bb0, bb1);
        ht[el1 * 17 + lane] = h1pack(pu1, qu1, d1, i1, w1l0, w1l1, bb0, bb1);
      }
    } else {
      #pragma unroll 2
      for (int rr = 0; rr < 16; ++rr) {
        int el = rr * 16 + grp;
        int e  = base + el;
        if (e < E) {
          int rs = sRS[el], rt = sRT[el];
          float dist;
          if (FQ) {
#ifdef HAVE_FP8
            uint2 au = *(const uint2*)(featq + ((size_t)rs << 7) + (lane << 3));
            uint2 bu = *(const uint2*)(featq + ((size_t)rt << 7) + (lane << 3));
            dist = grp_dist_fp8(au, bu);
#else
            uint4 au = *(const uint4*)(featq + ((size_t)rs << 8) + (lane << 4));
            uint4 bu = *(const uint4*)(featq + ((size_t)rt << 8) + (lane << 4));
            dist = grp_dist_f16(au, bu);
#endif
          } else {
            const float4* A  = (const float4*)&feat[(size_t)rs * FEATD];
            const float4* Bp = (const float4*)&feat[(size_t)rt * FEATD];
            float ssd = 0.f;
            #pragma unroll
            for (int p = 0; p < 2; ++p) {
              float4 a = A[lane * 2 + p], c = Bp[lane * 2 + p];
              float dx = a.x - c.x, dy = a.y - c.y, dz = a.z - c.z, dw = a.w - c.w;
              ssd += dx * dx + dy * dy + dz * dz + dw * dw;
            }
            ssd += __shfl_xor(ssd, 1, 64);
            ssd += __shfl_xor(ssd, 2, 64);
            ssd += __shfl_xor(ssd, 4, 64);
            ssd += __shfl_xor(ssd, 8, 64);
            dist = sqrtf(ssd);
          }
          unsigned puv = *(const unsigned*)((const char*)p16 + ((size_t)rs << 7) + (lane << 2));
          unsigned quv = *(const unsigned*)((const char*)p16 + ((size_t)rt << 7) + 64 + (lane << 2));
          ht[el * 17 + lane] = h1pack(puv, quv, dist, i1, w1l0, w1l1, bb0, bb1);
        }
      }
    }
    __syncthreads();

    int e = base + tid;
    if (e < E) {
      unsigned hrow[16];
      #pragma unroll
      for (int q = 0; q < 16; ++q) hrow[q] = ht[tid * 17 + q];
      float la = bias3;
      #pragma unroll
      for (int j = 0; j < 32; ++j) {
        float acc = b2[j];
        #pragma unroll
        for (int q = 0; q < 16; ++q) {
          U32H2 w; w.u = w2h[j * 16 + q];
          U32H2 h; h.u = hrow[q];
          acc = fdot2f(w.h, h.h, acc);
        }
        la += ws[OFF_W3 + j] * fmaxf(acc, 0.f);
      }
      la = fminf(fmaxf(la, -5.f), 5.f);
      out[e]     = 1.0f / (1.0f + exp2f(la * -2.18590179f));
      out[E + e] = la;
    }
    __syncthreads();
  }
}

// ---------------- tiny-ws fallback: full spectral + in-loop W1, all f32 ----------------
template <int M, int K>
__device__ float spectral_sigma_t(const float* __restrict__ Wg,
                                  float* sW, float* u, float* v, volatile float* red) {
  int tid = threadIdx.x;
  int wid = tid >> 6, lid = tid & 63;
  int j8 = tid >> 3, l8 = tid & 7;
  for (int i = tid; i < M * K; i += 256) sW[i] = Wg[i];
  if (tid < M) u[tid] = 1.0f;
  __syncthreads();
  float invu = 1.0f / sqrtf((float)M);
  float invv = 0.f;
  for (int it = 0; it < 5; ++it) {
    float p = 0.f;
    for (int k = tid; k < K; k += 256) {
      float a = 0.f;
      #pragma unroll
      for (int j = 0; j < M; ++j) a += sW[j * K + k] * u[j];
      a *= invu;
      v[k] = a;
      p += a * a;
    }
    #pragma unroll
    for (int off = 1; off < 64; off <<= 1) p += __shfl_xor(p, off, 64);
    if (lid == 0) red[wid] = p;
    __syncthreads();
    p = red[0] + red[1] + red[2] + red[3];
    invv = 1.0f / (sqrtf(p) + 1e-12f);
    float a = 0.f;
    if (j8 < M) {
      #pragma unroll
      for (int k = l8; k < K; k += 8) a += sW[j8 * K + k] * v[k];
      a *= invv;
    }
    a += __shfl_xor(a, 1, 64);
    a += __shfl_xor(a, 2, 64);
    a += __shfl_xor(a, 4, 64);
    float q = 0.f;
    if (j8 < M && l8 == 0) { u[j8] = a; q = a * a; }
    #pragma unroll
    for (int off = 1; off < 64; off <<= 1) q += __shfl_xor(q, off, 64);
    if (lid == 0) red[4 + wid] = q;
    __syncthreads();
    q = red[4] + red[5] + red[6] + red[7];
    invu = 1.0f / (sqrtf(q) + 1e-12f);
  }
  float a = 0.f;
  if (j8 < M) {
    #pragma unroll
    for (int k = l8; k < K; k += 8) a += sW[j8 * K + k] * v[k];
  }
  a += __shfl_xor(a, 1, 64);
  a += __shfl_xor(a, 2, 64);
  a += __shfl_xor(a, 4, 64);
  float s = (j8 < M && l8 == 0) ? a * u[j8] : 0.f;
  #pragma unroll
  for (int off = 1; off < 64; off <<= 1) s += __shfl_xor(s, off, 64);
  if (lid == 0) red[wid] = s;
  __syncthreads();
  float sig = (red[0] + red[1] + red[2] + red[3]) * invu * invv;
  __syncthreads();
  return sig;
}

__global__ __launch_bounds__(256) void spectral_full(const float* __restrict__ W1,
                                                     const float* __restrict__ W2,
                                                     const float* __restrict__ W3,
                                                     float* __restrict__ ws) {
  __shared__ float sA[32 * 257];
  __shared__ float u[32], v[257];
  __shared__ float red[8];
  int tid = threadIdx.x;
  float sig1 = spectral_sigma_t<32, 257>(W1, sA, u, v, red);
  float i1 = 1.0f / sig1;
  for (int idx = tid; idx < 128 * 64; idx += 256) {
    int k = idx >> 6, jj = idx & 63;
    float w = (jj < 32) ? sA[jj * 257 + k] : sA[(jj - 32) * 257 + 128 + k];
    ws[OFF_FBWT + idx] = w * i1;
  }
  for (int j = tid; j < 32; j += 256) ws[OFF_W1L + j] = sA[j * 257 + 256] * i1;
  __syncthreads();
  float sig2 = spectral_sigma_t<32, 32>(W2, sA, u, v, red);
  float i2 = 1.0f / sig2;
  for (int idx = tid; idx < 1024; idx += 256) ws[OFF_W2 + idx] = sA[idx] * i2;
  __syncthreads();
  float sig3 = spectral_sigma_t<1, 32>(W3, sA, u, v, red);
  float i3 = 1.0f / sig3;
  for (int k = tid; k < 32; k += 256) ws[OFF_W3 + k] = sA[k] * i3;
}

__global__ __launch_bounds__(256) void edge_kernel_nop(const float* __restrict__ feat,
                                                       const float* __restrict__ ws,
                                                       const float* __restrict__ b1,
                                                       const float* __restrict__ b2,
                                                       const float* __restrict__ b3,
                                                       const int* __restrict__ bids,
                                                       const int* __restrict__ srcs,
                                                       const int* __restrict__ tgts,
                                                       float* __restrict__ out, int E) {
  __shared__ float sWt[128 * 64];
  __shared__ float sW2[1024];
  __shared__ float sW3[32], sW1l[32], sB1[32], sB2[32];
  int tid = threadIdx.x;
  for (int i = tid * 4; i < 128 * 64; i += 256 * 4)
    *(float4*)&sWt[i] = *(const float4*)&ws[OFF_FBWT + i];
  for (int i = tid; i < 1024; i += 256) sW2[i] = ws[OFF_W2 + i];
  if (tid < 32) {
    sW3[tid]  = ws[OFF_W3 + tid];
    sW1l[tid] = ws[OFF_W1L + tid];
    sB1[tid]  = b1[tid];
    sB2[tid]  = b2[tid];
  }
  __syncthreads();
  float bias3 = b3[0];

  for (int e = blockIdx.x * 256 + tid; e < E; e += gridDim.x * 256) {
    int b = bids[e], s = srcs[e], t = tgts[e];
    const float4* A  = (const float4*)&feat[(size_t)(b * NNODES + s) * FEATD];
    const float4* Bp = (const float4*)&feat[(size_t)(b * NNODES + t) * FEATD];
    float ssd = 0.f;
    float h1p[32];
    #pragma unroll
    for (int j = 0; j < 32; ++j) h1p[j] = 0.f;
    #pragma unroll 1
    for (int k4 = 0; k4 < 32; ++k4) {
      float4 a = A[k4], c = Bp[k4];
      float dx = a.x - c.x, dy = a.y - c.y, dz = a.z - c.z, dw = a.w - c.w;
      ssd += dx * dx + dy * dy + dz * dz + dw * dw;
      #pragma unroll
      for (int kk = 0; kk < 4; ++kk) {
        int k = 4 * k4 + kk;
        float fa = (kk == 0) ? a.x : (kk == 1) ? a.y : (kk == 2) ? a.z : a.w;
        float fc = (kk == 0) ? c.x : (kk == 1) ? c.y : (kk == 2) ? c.z : c.w;
        #pragma unroll
        for (int q = 0; q < 8; ++q) {
          float4 w0 = *(const float4*)&sWt[k * 64 + 4 * q];
          float4 w1 = *(const float4*)&sWt[k * 64 + 32 + 4 * q];
          h1p[4*q+0] += fa * w0.x + fc * w1.x;
          h1p[4*q+1] += fa * w0.y + fc * w1.y;
          h1p[4*q+2] += fa * w0.z + fc * w1.z;
          h1p[4*q+3] += fa * w0.w + fc * w1.w;
        }
      }
    }
    float dist = sqrtf(ssd);
    float h1[32];
    #pragma unroll
    for (int j = 0; j < 32; ++j)
      h1[j] = fmaxf(h1p[j] + dist * sW1l[j] + sB1[j], 0.f);
    float la = bias3;
    #pragma unroll
    for (int j = 0; j < 32; ++j) {
      float acc = sB2[j];
      #pragma unroll
      for (int q = 0; q < 8; ++q) {
        float4 w = *(const float4*)&sW2[j * 32 + 4 * q];
        acc += w.x * h1[4 * q] + w.y * h1[4 * q + 1] + w.z * h1[4 * q + 2] + w.w * h1[4 * q + 3];
      }
      la += sW3[j] * fmaxf(acc, 0.f);
    }
    la = fminf(fmaxf(la, -5.f), 5.f);
    out[e]     = 1.0f / (1.0f + __expf(-la / 0.66f));
    out[E + e] = la;
  }
}

extern "C" void kernel_launch(void* const* d_in, const int* in_sizes, int n_in,
                              void* d_out, int out_size, void* d_ws, size_t ws_size,
                              hipStream_t stream) {
  const float* feat = (const float*)d_in[0];
  const float* W1   = (const float*)d_in[1];
  const float* b1   = (const float*)d_in[2];
  const float* W2   = (const float*)d_in[3];
  const float* b2   = (const float*)d_in[4];
  const float* W3   = (const float*)d_in[5];
  const float* b3   = (const float*)d_in[6];
  const int* bids   = (const int*)d_in[7];
  const int* srcs   = (const int*)d_in[8];
  const int* tgts   = (const int*)d_in[9];
  float* out = (float*)d_out;
  float* ws  = (float*)d_ws;
  int E = in_sizes[7];

  size_t need_p  = (size_t)OFF_FQ * sizeof(float);                  // P16 only
  size_t need_fq = (size_t)(OFF_FQ + F16_FLOATS) * sizeof(float);   // + feat copy (worst case)
  int egrid = (E + 255) / 256;

  if (ws_size >= need_fq) {
    spectral64<<<dim3(1), dim3(64), 0, stream>>>(W1, W2, W3, ws);
    proj_kernel<<<dim3(625), dim3(256), 0, stream>>>(feat, W1, ws, 1);
    edge_fused<true><<<dim3(egrid), dim3(256), 0, stream>>>(feat, ws, b1, b2, b3,
                                                            bids, srcs, tgts, out, E);
  } else if (ws_size >= need_p) {
    spectral64<<<dim3(1), dim3(64), 0, stream>>>(W1, W2, W3, ws);
    proj_kernel<<<dim3(625), dim3(256), 0, stream>>>(feat, W1, ws, 0);
    edge_fused<false><<<dim3(egrid), dim3(256), 0, stream>>>(feat, ws, b1, b2, b3,
                                                             bids, srcs, tgts, out, E);
  } else {
    spectral_full<<<dim3(1), dim3(256), 0, stream>>>(W1, W2, W3, ws);
    edge_kernel_nop<<<dim3(egrid), dim3(256), 0, stream>>>(feat, ws, b1, b2, b3,
                                                           bids, srcs, tgts, out, E);
  }
}

// Round 14
// 91.220 us; speedup vs baseline: 1.2608x; 1.2608x over previous
//
#include <hip/hip_runtime.h>
#include <hip/hip_fp16.h>
#include <math.h>

#define FEATD 128
#define NNODES 10000
#define NBATCH 4
#define NROWS (NBATCH*NNODES)   // 40000

// ws layout (float slots, 4B each)
#define OFF_I1   0                     // 1/sigma1
#define OFF_W1L  8                     // w1last normalized [32] f32
#define OFF_W2   64                    // W2 normalized [32*32] f32 (fallback only)
#define OFF_W3   1088                  // W3 normalized [32] f32
#define OFF_W2H  1120                  // W2 normalized half2 [512 uint slots]
#define OFF_P16  4096                  // P16 raw proj [40000][64] half (5.12 MB)
#define P16_FLOATS (NROWS*64/2)        // 1,280,000 float slots
#define OFF_FQ   (OFF_P16 + P16_FLOATS) // featq: fp8 [40000][128] (5.12MB) or f16 (10.24MB)
#define F16_FLOATS (NROWS*FEATD/2)     // worst case float slots
#define OFF_FBWT OFF_P16               // fallback: normalized Wt[128][64] f32

#define WSTRIDE 68                     // padded k-row stride (bank-conflict fix, R8-verified)

typedef _Float16 h2 __attribute__((ext_vector_type(2)));
union U32H2 { unsigned u; h2 h; };
union U4H2  { uint4 u; h2 h[4]; };

#if defined(__has_builtin)
#if __has_builtin(__builtin_amdgcn_fdot2)
#define HAVE_FDOT2 1
#endif
#if __has_builtin(__builtin_amdgcn_cvt_pk_f32_fp8) && __has_builtin(__builtin_amdgcn_cvt_pk_fp8_f32)
#define HAVE_FP8 1
#endif
#endif

__device__ __forceinline__ float fdot2f(h2 a, h2 b, float c) {
#ifdef HAVE_FDOT2
  return __builtin_amdgcn_fdot2(a, b, c, false);
#else
  return c + (float)a[0] * (float)b[0] + (float)a[1] * (float)b[1];
#endif
}

#ifdef HAVE_FP8
typedef float floatx2 __attribute__((ext_vector_type(2)));
__device__ __forceinline__ float ssd_fp8_w(unsigned aw, unsigned bw, float s) {
  floatx2 al = __builtin_amdgcn_cvt_pk_f32_fp8((int)aw, false);
  floatx2 ah = __builtin_amdgcn_cvt_pk_f32_fp8((int)aw, true);
  floatx2 bl = __builtin_amdgcn_cvt_pk_f32_fp8((int)bw, false);
  floatx2 bh = __builtin_amdgcn_cvt_pk_f32_fp8((int)bw, true);
  float d0 = al[0] - bl[0], d1 = al[1] - bl[1];
  float d2 = ah[0] - bh[0], d3 = ah[1] - bh[1];
  return s + d0 * d0 + d1 * d1 + d2 * d2 + d3 * d3;
}
__device__ __forceinline__ float grp_dist_fp8(uint2 au, uint2 bu) {
  float ssd = ssd_fp8_w(au.x, bu.x, 0.f);
  ssd = ssd_fp8_w(au.y, bu.y, ssd);
  ssd += __shfl_xor(ssd, 1, 64);
  ssd += __shfl_xor(ssd, 2, 64);
  ssd += __shfl_xor(ssd, 4, 64);
  ssd += __shfl_xor(ssd, 8, 64);
  return sqrtf(ssd);
}
#endif

// ------------- spectral sigma: exact reference power iteration (R11-verified) -------------
template <int M, int K>
__device__ float spectral_sigma_t(const float* __restrict__ Wg,
                                  float* sW, float* u, float* v, volatile float* red) {
  int tid = threadIdx.x;
  int wid = tid >> 6, lid = tid & 63;
  int j8 = tid >> 3, l8 = tid & 7;
  for (int i = tid; i < M * K; i += 256) sW[i] = Wg[i];
  if (tid < M) u[tid] = 1.0f;
  __syncthreads();
  float invu = 1.0f / sqrtf((float)M);
  float invv = 0.f;

  for (int it = 0; it < 5; ++it) {
    float p = 0.f;
    for (int k = tid; k < K; k += 256) {
      float a = 0.f;
      #pragma unroll
      for (int j = 0; j < M; ++j) a += sW[j * K + k] * u[j];
      a *= invu;
      v[k] = a;
      p += a * a;
    }
    #pragma unroll
    for (int off = 1; off < 64; off <<= 1) p += __shfl_xor(p, off, 64);
    if (lid == 0) red[wid] = p;
    __syncthreads();
    p = red[0] + red[1] + red[2] + red[3];
    invv = 1.0f / (sqrtf(p) + 1e-12f);

    float a = 0.f;
    if (j8 < M) {
      #pragma unroll
      for (int k = l8; k < K; k += 8) a += sW[j8 * K + k] * v[k];
      a *= invv;
    }
    a += __shfl_xor(a, 1, 64);
    a += __shfl_xor(a, 2, 64);
    a += __shfl_xor(a, 4, 64);
    float q = 0.f;
    if (j8 < M && l8 == 0) { u[j8] = a; q = a * a; }
    #pragma unroll
    for (int off = 1; off < 64; off <<= 1) q += __shfl_xor(q, off, 64);
    if (lid == 0) red[4 + wid] = q;
    __syncthreads();
    q = red[4] + red[5] + red[6] + red[7];
    invu = 1.0f / (sqrtf(q) + 1e-12f);
  }

  float a = 0.f;
  if (j8 < M) {
    #pragma unroll
    for (int k = l8; k < K; k += 8) a += sW[j8 * K + k] * v[k];
  }
  a += __shfl_xor(a, 1, 64);
  a += __shfl_xor(a, 2, 64);
  a += __shfl_xor(a, 4, 64);
  float s = (j8 < M && l8 == 0) ? a * u[j8] : 0.f;
  #pragma unroll
  for (int off = 1; off < 64; off <<= 1) s += __shfl_xor(s, off, 64);
  if (lid == 0) red[wid] = s;
  __syncthreads();
  float sig = (red[0] + red[1] + red[2] + red[3]) * invu * invv;
  __syncthreads();
  return sig;
}

// ---------------- fused prep kernel (EXACT R11 structure, measured 37us) ----------------
__global__ __launch_bounds__(256, 4) void prep_kernel(const float* __restrict__ feat,
                                                      const float* __restrict__ W1,
                                                      const float* __restrict__ W2,
                                                      const float* __restrict__ W3,
                                                      float* __restrict__ ws,
                                                      int doFQ) {
  __shared__ float sA[128 * WSTRIDE];
  __shared__ float u[32], v[257];
  __shared__ float red[8];
  int tid = threadIdx.x;

  if (blockIdx.x == 0) {
    float sig1 = spectral_sigma_t<32, 257>(W1, sA, u, v, red);
    float i1 = 1.0f / sig1;
    if (tid == 0) ws[OFF_I1] = i1;
    for (int j = tid; j < 32; j += 256) ws[OFF_W1L + j] = sA[j * 257 + 256] * i1;
    __syncthreads();
    float sig2 = spectral_sigma_t<32, 32>(W2, sA, u, v, red);
    float i2 = 1.0f / sig2;
    for (int idx = tid; idx < 1024; idx += 256) ws[OFF_W2 + idx] = sA[idx] * i2;
    unsigned* w2h = (unsigned*)(ws + OFF_W2H);
    for (int idx = tid; idx < 512; idx += 256) {
      int j = idx >> 4, q = idx & 15;
      U32H2 pk;
      pk.h[0] = (_Float16)(sA[j * 32 + 2 * q] * i2);
      pk.h[1] = (_Float16)(sA[j * 32 + 2 * q + 1] * i2);
      w2h[idx] = pk.u;
    }
    __syncthreads();
    float sig3 = spectral_sigma_t<1, 32>(W3, sA, u, v, red);
    float i3 = 1.0f / sig3;
    for (int k = tid; k < 32; k += 256) ws[OFF_W3 + k] = sA[k] * i3;
    return;
  }

  // projection path: stage RAW W1 transposed with padded stride
  for (int idx = tid; idx < 32 * 257; idx += 256) {
    int j = idx / 257, c = idx - j * 257;
    float w = W1[idx];
    if (c < 128) sA[c * WSTRIDE + j] = w;
    else if (c < 256) sA[(c - 128) * WSTRIDE + 32 + j] = w;
  }
  __syncthreads();

  __half* p16 = (__half*)(ws + OFF_P16);
  char* fq = (char*)(ws + OFF_FQ);
  int rg = tid >> 4;
  int jg = (tid & 15) << 2;
  int slice = tid & 15;
  int r0 = (blockIdx.x - 1) * 64 + rg * 4;
  const float4* F0 = (const float4*)&feat[(size_t)(r0 + 0) * FEATD];
  const float4* F1 = (const float4*)&feat[(size_t)(r0 + 1) * FEATD];
  const float4* F2 = (const float4*)&feat[(size_t)(r0 + 2) * FEATD];
  const float4* F3 = (const float4*)&feat[(size_t)(r0 + 3) * FEATD];
  float acc[4][4] = {{0,0,0,0},{0,0,0,0},{0,0,0,0},{0,0,0,0}};

  #pragma unroll 2
  for (int k4 = 0; k4 < 32; ++k4) {
    float4 f0 = F0[k4], f1 = F1[k4], f2 = F2[k4], f3 = F3[k4];
    if (doFQ && (k4 >> 1) == slice) {
#ifdef HAVE_FP8
      unsigned w;
      w = __builtin_amdgcn_cvt_pk_fp8_f32(f0.x, f0.y, 0, false);
      w = __builtin_amdgcn_cvt_pk_fp8_f32(f0.z, f0.w, (int)w, true);
      *(unsigned*)(fq + (size_t)(r0 + 0) * 128 + (size_t)k4 * 4) = w;
      w = __builtin_amdgcn_cvt_pk_fp8_f32(f1.x, f1.y, 0, false);
      w = __builtin_amdgcn_cvt_pk_fp8_f32(f1.z, f1.w, (int)w, true);
      *(unsigned*)(fq + (size_t)(r0 + 1) * 128 + (size_t)k4 * 4) = w;
      w = __builtin_amdgcn_cvt_pk_fp8_f32(f2.x, f2.y, 0, false);
      w = __builtin_amdgcn_cvt_pk_fp8_f32(f2.z, f2.w, (int)w, true);
      *(unsigned*)(fq + (size_t)(r0 + 2) * 128 + (size_t)k4 * 4) = w;
      w = __builtin_amdgcn_cvt_pk_fp8_f32(f3.x, f3.y, 0, false);
      w = __builtin_amdgcn_cvt_pk_fp8_f32(f3.z, f3.w, (int)w, true);
      *(unsigned*)(fq + (size_t)(r0 + 3) * 128 + (size_t)k4 * 4) = w;
#else
      U32H2 a, b; uint2 pk;
      a.h[0]=(_Float16)f0.x; a.h[1]=(_Float16)f0.y; b.h[0]=(_Float16)f0.z; b.h[1]=(_Float16)f0.w;
      pk.x=a.u; pk.y=b.u; *(uint2*)(fq + (size_t)(r0+0)*256 + (size_t)k4*8) = pk;
      a.h[0]=(_Float16)f1.x; a.h[1]=(_Float16)f1.y; b.h[0]=(_Float16)f1.z; b.h[1]=(_Float16)f1.w;
      pk.x=a.u; pk.y=b.u; *(uint2*)(fq + (size_t)(r0+1)*256 + (size_t)k4*8) = pk;
      a.h[0]=(_Float16)f2.x; a.h[1]=(_Float16)f2.y; b.h[0]=(_Float16)f2.z; b.h[1]=(_Float16)f2.w;
      pk.x=a.u; pk.y=b.u; *(uint2*)(fq + (size_t)(r0+2)*256 + (size_t)k4*8) = pk;
      a.h[0]=(_Float16)f3.x; a.h[1]=(_Float16)f3.y; b.h[0]=(_Float16)f3.z; b.h[1]=(_Float16)f3.w;
      pk.x=a.u; pk.y=b.u; *(uint2*)(fq + (size_t)(r0+3)*256 + (size_t)k4*8) = pk;
#endif
    }
    #pragma unroll
    for (int kk = 0; kk < 4; ++kk) {
      int k = 4 * k4 + kk;
      float4 w = *(const float4*)&sA[k * WSTRIDE + jg];
      float e0 = (kk == 0) ? f0.x : (kk == 1) ? f0.y : (kk == 2) ? f0.z : f0.w;
      float e1 = (kk == 0) ? f1.x : (kk == 1) ? f1.y : (kk == 2) ? f1.z : f1.w;
      float e2 = (kk == 0) ? f2.x : (kk == 1) ? f2.y : (kk == 2) ? f2.z : f2.w;
      float e3 = (kk == 0) ? f3.x : (kk == 1) ? f3.y : (kk == 2) ? f3.z : f3.w;
      acc[0][0] += e0 * w.x; acc[0][1] += e0 * w.y; acc[0][2] += e0 * w.z; acc[0][3] += e0 * w.w;
      acc[1][0] += e1 * w.x; acc[1][1] += e1 * w.y; acc[1][2] += e1 * w.z; acc[1][3] += e1 * w.w;
      acc[2][0] += e2 * w.x; acc[2][1] += e2 * w.y; acc[2][2] += e2 * w.z; acc[2][3] += e2 * w.w;
      acc[3][0] += e3 * w.x; acc[3][1] += e3 * w.y; acc[3][2] += e3 * w.z; acc[3][3] += e3 * w.w;
    }
  }
  #pragma unroll
  for (int r = 0; r < 4; ++r) {
    U32H2 a, b;
    a.h[0] = (_Float16)acc[r][0]; a.h[1] = (_Float16)acc[r][1];
    b.h[0] = (_Float16)acc[r][2]; b.h[1] = (_Float16)acc[r][3];
    uint2 o; o.x = a.u; o.y = b.u;
    *(uint2*)((char*)p16 + (size_t)(r0 + r) * 128 + (size_t)jg * 2) = o;
  }
}

// ---------------- edge kernel helpers ----------------
__device__ __forceinline__ float grp_dist_f16(uint4 au, uint4 bu) {
  U4H2 a, b; a.u = au; b.u = bu;
  float ssd = 0.f;
  #pragma unroll
  for (int p = 0; p < 4; ++p) { h2 d = a.h[p] - b.h[p]; ssd = fdot2f(d, d, ssd); }
  ssd += __shfl_xor(ssd, 1, 64);
  ssd += __shfl_xor(ssd, 2, 64);
  ssd += __shfl_xor(ssd, 4, 64);
  ssd += __shfl_xor(ssd, 8, 64);
  return sqrtf(ssd);
}

__device__ __forceinline__ unsigned h1pack(unsigned puv, unsigned quv, float dist, float i1,
                                           float w1l0, float w1l1, float bb0, float bb1) {
  U32H2 p, q; p.u = puv; q.u = quv;
  float h0  = fmaxf(fmaf((float)p.h[0] + (float)q.h[0], i1, fmaf(dist, w1l0, bb0)), 0.f);
  float h1v = fmaxf(fmaf((float)p.h[1] + (float)q.h[1], i1, fmaf(dist, w1l1, bb1)), 0.f);
  U32H2 r; r.h[0] = (_Float16)h0; r.h[1] = (_Float16)h1v;
  return r.u;
}

// ---------------- barrier-free edge kernel: wave-autonomous 64-edge tiles ----------------
// Indices via __shfl broadcast (no sRS staging); ht tile wave-private; ZERO __syncthreads.
template <bool FQ>
__global__ __launch_bounds__(256, 8) void edge_wave(const float* __restrict__ feat,
                                                    const float* __restrict__ ws,
                                                    const float* __restrict__ b1,
                                                    const float* __restrict__ b2,
                                                    const float* __restrict__ b3,
                                                    const int* __restrict__ bids,
                                                    const int* __restrict__ srcs,
                                                    const int* __restrict__ tgts,
                                                    float* __restrict__ out, int E) {
  __shared__ unsigned ht[4 * 64 * 17];   // 17.4 KB, one 64x17 tile per wave
  int tid = threadIdx.x;
  int wv   = tid >> 6;
  int l64  = tid & 63;
  int grp  = l64 >> 4;      // 0..3 group within wave
  int lane = l64 & 15;
  unsigned* htw = &ht[wv * 64 * 17];

  const char*  featq = (const char*)(ws + OFF_FQ);
  const __half* p16  = (const __half*)(ws + OFF_P16);
  const unsigned* w2h = (const unsigned*)(ws + OFF_W2H);

  float i1 = ws[OFF_I1];
  int j0 = 2 * lane;
  float w1l0 = ws[OFF_W1L + j0];
  float w1l1 = ws[OFF_W1L + j0 + 1];
  float bb0  = b1[j0];
  float bb1  = b1[j0 + 1];
  float bias3 = b3[0];

  int wstep = gridDim.x * 4 * 64;
  for (int base = (blockIdx.x * 4 + wv) * 64; base < E; base += wstep) {
    int e = base + l64;
    int rs_m = 0, rt_m = 0;
    if (e < E) {
      int b = bids[e];
      rs_m = b * NNODES + srcs[e];
      rt_m = b * NNODES + tgts[e];
    }

    // ---- phase 1: group processes its 16 edges, 4-edge batched prefetch ----
    if (FQ && (base + 64 <= E)) {
      int elb = grp << 4;
      #pragma unroll 1
      for (int rr = 0; rr < 4; ++rr) {
        int el0 = elb + 4 * rr + 0;
        int el1 = elb + 4 * rr + 1;
        int el2 = elb + 4 * rr + 2;
        int el3 = elb + 4 * rr + 3;
        int rs0 = __shfl(rs_m, el0, 64), rt0 = __shfl(rt_m, el0, 64);
        int rs1 = __shfl(rs_m, el1, 64), rt1 = __shfl(rt_m, el1, 64);
        int rs2 = __shfl(rs_m, el2, 64), rt2 = __shfl(rt_m, el2, 64);
        int rs3 = __shfl(rs_m, el3, 64), rt3 = __shfl(rt_m, el3, 64);
#ifdef HAVE_FP8
        uint2 a0 = *(const uint2*)(featq + ((size_t)rs0 << 7) + (lane << 3));
        uint2 c0 = *(const uint2*)(featq + ((size_t)rt0 << 7) + (lane << 3));
        uint2 a1 = *(const uint2*)(featq + ((size_t)rs1 << 7) + (lane << 3));
        uint2 c1 = *(const uint2*)(featq + ((size_t)rt1 << 7) + (lane << 3));
        uint2 a2 = *(const uint2*)(featq + ((size_t)rs2 << 7) + (lane << 3));
        uint2 c2 = *(const uint2*)(featq + ((size_t)rt2 << 7) + (lane << 3));
        uint2 a3 = *(const uint2*)(featq + ((size_t)rs3 << 7) + (lane << 3));
        uint2 c3 = *(const uint2*)(featq + ((size_t)rt3 << 7) + (lane << 3));
#else
        uint4 a0 = *(const uint4*)(featq + ((size_t)rs0 << 8) + (lane << 4));
        uint4 c0 = *(const uint4*)(featq + ((size_t)rt0 << 8) + (lane << 4));
        uint4 a1 = *(const uint4*)(featq + ((size_t)rs1 << 8) + (lane << 4));
        uint4 c1 = *(const uint4*)(featq + ((size_t)rt1 << 8) + (lane << 4));
        uint4 a2 = *(const uint4*)(featq + ((size_t)rs2 << 8) + (lane << 4));
        uint4 c2 = *(const uint4*)(featq + ((size_t)rt2 << 8) + (lane << 4));
        uint4 a3 = *(const uint4*)(featq + ((size_t)rs3 << 8) + (lane << 4));
        uint4 c3 = *(const uint4*)(featq + ((size_t)rt3 << 8) + (lane << 4));
#endif
        unsigned pu0 = *(const unsigned*)((const char*)p16 + ((size_t)rs0 << 7) + (lane << 2));
        unsigned qu0 = *(const unsigned*)((const char*)p16 + ((size_t)rt0 << 7) + 64 + (lane << 2));
        unsigned pu1 = *(const unsigned*)((const char*)p16 + ((size_t)rs1 << 7) + (lane << 2));
        unsigned qu1 = *(const unsigned*)((const char*)p16 + ((size_t)rt1 << 7) + 64 + (lane << 2));
        unsigned pu2 = *(const unsigned*)((const char*)p16 + ((size_t)rs2 << 7) + (lane << 2));
        unsigned qu2 = *(const unsigned*)((const char*)p16 + ((size_t)rt2 << 7) + 64 + (lane << 2));
        unsigned pu3 = *(const unsigned*)((const char*)p16 + ((size_t)rs3 << 7) + (lane << 2));
        unsigned qu3 = *(const unsigned*)((const char*)p16 + ((size_t)rt3 << 7) + 64 + (lane << 2));
#ifdef HAVE_FP8
        float d0 = grp_dist_fp8(a0, c0);
        float d1 = grp_dist_fp8(a1, c1);
        float d2 = grp_dist_fp8(a2, c2);
        float d3 = grp_dist_fp8(a3, c3);
#else
        float d0 = grp_dist_f16(a0, c0);
        float d1 = grp_dist_f16(a1, c1);
        float d2 = grp_dist_f16(a2, c2);
        float d3 = grp_dist_f16(a3, c3);
#endif
        htw[el0 * 17 + lane] = h1pack(pu0, qu0, d0, i1, w1l0, w1l1, bb0, bb1);
        htw[el1 * 17 + lane] = h1pack(pu1, qu1, d1, i1, w1l0, w1l1, bb0, bb1);
        htw[el2 * 17 + lane] = h1pack(pu2, qu2, d2, i1, w1l0, w1l1, bb0, bb1);
        htw[el3 * 17 + lane] = h1pack(pu3, qu3, d3, i1, w1l0, w1l1, bb0, bb1);
      }
    } else {
      // guarded tail / non-FQ path
      int elb = grp << 4;
      #pragma unroll 2
      for (int r = 0; r < 16; ++r) {
        int el = elb + r;
        if (base + el < E) {
          int rs = __shfl(rs_m, el, 64), rt = __shfl(rt_m, el, 64);
          float dist;
          if (FQ) {
#ifdef HAVE_FP8
            uint2 au = *(const uint2*)(featq + ((size_t)rs << 7) + (lane << 3));
            uint2 bu = *(const uint2*)(featq + ((size_t)rt << 7) + (lane << 3));
            dist = grp_dist_fp8(au, bu);
#else
            uint4 au = *(const uint4*)(featq + ((size_t)rs << 8) + (lane << 4));
            uint4 bu = *(const uint4*)(featq + ((size_t)rt << 8) + (lane << 4));
            dist = grp_dist_f16(au, bu);
#endif
          } else {
            const float4* A  = (const float4*)&feat[(size_t)rs * FEATD];
            const float4* Bp = (const float4*)&feat[(size_t)rt * FEATD];
            float ssd = 0.f;
            #pragma unroll
            for (int p = 0; p < 2; ++p) {
              float4 a = A[lane * 2 + p], c = Bp[lane * 2 + p];
              float dx = a.x - c.x, dy = a.y - c.y, dz = a.z - c.z, dw = a.w - c.w;
              ssd += dx * dx + dy * dy + dz * dz + dw * dw;
            }
            ssd += __shfl_xor(ssd, 1, 64);
            ssd += __shfl_xor(ssd, 2, 64);
            ssd += __shfl_xor(ssd, 4, 64);
            ssd += __shfl_xor(ssd, 8, 64);
            dist = sqrtf(ssd);
          }
          unsigned puv = *(const unsigned*)((const char*)p16 + ((size_t)rs << 7) + (lane << 2));
          unsigned quv = *(const unsigned*)((const char*)p16 + ((size_t)rt << 7) + 64 + (lane << 2));
          htw[el * 17 + lane] = h1pack(puv, quv, dist, i1, w1l0, w1l1, bb0, bb1);
        }
      }
    }

    // ---- phase 2: thread-per-edge tail (same wave wrote htw -> no barrier needed) ----
    if (e < E) {
      unsigned hrow[16];
      #pragma unroll
      for (int q = 0; q < 16; ++q) hrow[q] = htw[l64 * 17 + q];
      float la = bias3;
      #pragma unroll
      for (int j = 0; j < 32; ++j) {
        float acc = b2[j];
        #pragma unroll
        for (int q = 0; q < 16; ++q) {
          U32H2 w; w.u = w2h[j * 16 + q];
          U32H2 h; h.u = hrow[q];
          acc = fdot2f(w.h, h.h, acc);
        }
        la += ws[OFF_W3 + j] * fmaxf(acc, 0.f);
      }
      la = fminf(fmaxf(la, -5.f), 5.f);
      out[e]     = 1.0f / (1.0f + exp2f(la * -2.18590179f));
      out[E + e] = la;
    }
  }
}

// ---------------- tiny-ws fallback: full spectral + in-loop W1, all f32 ----------------
__global__ __launch_bounds__(256) void spectral_full(const float* __restrict__ W1,
                                                     const float* __restrict__ W2,
                                                     const float* __restrict__ W3,
                                                     float* __restrict__ ws) {
  __shared__ float sA[32 * 257];
  __shared__ float u[32], v[257];
  __shared__ float red[8];
  int tid = threadIdx.x;
  float sig1 = spectral_sigma_t<32, 257>(W1, sA, u, v, red);
  float i1 = 1.0f / sig1;
  for (int idx = tid; idx < 128 * 64; idx += 256) {
    int k = idx >> 6, jj = idx & 63;
    float w = (jj < 32) ? sA[jj * 257 + k] : sA[(jj - 32) * 257 + 128 + k];
    ws[OFF_FBWT + idx] = w * i1;
  }
  for (int j = tid; j < 32; j += 256) ws[OFF_W1L + j] = sA[j * 257 + 256] * i1;
  __syncthreads();
  float sig2 = spectral_sigma_t<32, 32>(W2, sA, u, v, red);
  float i2 = 1.0f / sig2;
  for (int idx = tid; idx < 1024; idx += 256) ws[OFF_W2 + idx] = sA[idx] * i2;
  __syncthreads();
  float sig3 = spectral_sigma_t<1, 32>(W3, sA, u, v, red);
  float i3 = 1.0f / sig3;
  for (int k = tid; k < 32; k += 256) ws[OFF_W3 + k] = sA[k] * i3;
}

__global__ __launch_bounds__(256) void edge_kernel_nop(const float* __restrict__ feat,
                                                       const float* __restrict__ ws,
                                                       const float* __restrict__ b1,
                                                       const float* __restrict__ b2,
                                                       const float* __restrict__ b3,
                                                       const int* __restrict__ bids,
                                                       const int* __restrict__ srcs,
                                                       const int* __restrict__ tgts,
                                                       float* __restrict__ out, int E) {
  __shared__ float sWt[128 * 64];
  __shared__ float sW2[1024];
  __shared__ float sW3[32], sW1l[32], sB1[32], sB2[32];
  int tid = threadIdx.x;
  for (int i = tid * 4; i < 128 * 64; i += 256 * 4)
    *(float4*)&sWt[i] = *(const float4*)&ws[OFF_FBWT + i];
  for (int i = tid; i < 1024; i += 256) sW2[i] = ws[OFF_W2 + i];
  if (tid < 32) {
    sW3[tid]  = ws[OFF_W3 + tid];
    sW1l[tid] = ws[OFF_W1L + tid];
    sB1[tid]  = b1[tid];
    sB2[tid]  = b2[tid];
  }
  __syncthreads();
  float bias3 = b3[0];

  for (int e = blockIdx.x * 256 + tid; e < E; e += gridDim.x * 256) {
    int b = bids[e], s = srcs[e], t = tgts[e];
    const float4* A  = (const float4*)&feat[(size_t)(b * NNODES + s) * FEATD];
    const float4* Bp = (const float4*)&feat[(size_t)(b * NNODES + t) * FEATD];
    float ssd = 0.f;
    float h1p[32];
    #pragma unroll
    for (int j = 0; j < 32; ++j) h1p[j] = 0.f;
    #pragma unroll 1
    for (int k4 = 0; k4 < 32; ++k4) {
      float4 a = A[k4], c = Bp[k4];
      float dx = a.x - c.x, dy = a.y - c.y, dz = a.z - c.z, dw = a.w - c.w;
      ssd += dx * dx + dy * dy + dz * dz + dw * dw;
      #pragma unroll
      for (int kk = 0; kk < 4; ++kk) {
        int k = 4 * k4 + kk;
        float fa = (kk == 0) ? a.x : (kk == 1) ? a.y : (kk == 2) ? a.z : a.w;
        float fc = (kk == 0) ? c.x : (kk == 1) ? c.y : (kk == 2) ? c.z : c.w;
        #pragma unroll
        for (int q = 0; q < 8; ++q) {
          float4 w0 = *(const float4*)&sWt[k * 64 + 4 * q];
          float4 w1 = *(const float4*)&sWt[k * 64 + 32 + 4 * q];
          h1p[4*q+0] += fa * w0.x + fc * w1.x;
          h1p[4*q+1] += fa * w0.y + fc * w1.y;
          h1p[4*q+2] += fa * w0.z + fc * w1.z;
          h1p[4*q+3] += fa * w0.w + fc * w1.w;
        }
      }
    }
    float dist = sqrtf(ssd);
    float h1[32];
    #pragma unroll
    for (int j = 0; j < 32; ++j)
      h1[j] = fmaxf(h1p[j] + dist * sW1l[j] + sB1[j], 0.f);
    float la = bias3;
    #pragma unroll
    for (int j = 0; j < 32; ++j) {
      float acc = sB2[j];
      #pragma unroll
      for (int q = 0; q < 8; ++q) {
        float4 w = *(const float4*)&sW2[j * 32 + 4 * q];
        acc += w.x * h1[4 * q] + w.y * h1[4 * q + 1] + w.z * h1[4 * q + 2] + w.w * h1[4 * q + 3];
      }
      la += sW3[j] * fmaxf(acc, 0.f);
    }
    la = fminf(fmaxf(la, -5.f), 5.f);
    out[e]     = 1.0f / (1.0f + __expf(-la / 0.66f));
    out[E + e] = la;
  }
}

extern "C" void kernel_launch(void* const* d_in, const int* in_sizes, int n_in,
                              void* d_out, int out_size, void* d_ws, size_t ws_size,
                              hipStream_t stream) {
  const float* feat = (const float*)d_in[0];
  const float* W1   = (const float*)d_in[1];
  const float* b1   = (const float*)d_in[2];
  const float* W2   = (const float*)d_in[3];
  const float* b2   = (const float*)d_in[4];
  const float* W3   = (const float*)d_in[5];
  const float* b3   = (const float*)d_in[6];
  const int* bids   = (const int*)d_in[7];
  const int* srcs   = (const int*)d_in[8];
  const int* tgts   = (const int*)d_in[9];
  float* out = (float*)d_out;
  float* ws  = (float*)d_ws;
  int E = in_sizes[7];

  size_t need_p  = (size_t)OFF_FQ * sizeof(float);
  size_t need_fq = (size_t)(OFF_FQ + F16_FLOATS) * sizeof(float);
  int egrid = (E + 255) / 256;

  if (ws_size >= need_fq) {
    prep_kernel<<<dim3(626), dim3(256), 0, stream>>>(feat, W1, W2, W3, ws, 1);
    edge_wave<true><<<dim3(egrid), dim3(256), 0, stream>>>(feat, ws, b1, b2, b3,
                                                           bids, srcs, tgts, out, E);
  } else if (ws_size >= need_p) {
    prep_kernel<<<dim3(626), dim3(256), 0, stream>>>(feat, W1, W2, W3, ws, 0);
    edge_wave<false><<<dim3(egrid), dim3(256), 0, stream>>>(feat, ws, b1, b2, b3,
                                                            bids, srcs, tgts, out, E);
  } else {
    spectral_full<<<dim3(1), dim3(256), 0, stream>>>(W1, W2, W3, ws);
    edge_kernel_nop<<<dim3(egrid), dim3(256), 0, stream>>>(feat, ws, b1, b2, b3,
                                                           bids, srcs, tgts, out, E);
  }
}